// Round 2
// baseline (213.644 us; speedup 1.0000x reference)
//
#include <hip/hip_runtime.h>

// Geometry: B=4, C=96 (F=32 lights x 3), H=W=256.  NCHW fp32.
// Element (b,c,h,w) at ((b*96+c)*65536 + h*256 + w). Output (4,3,256,256) fp32.
//
// R1 design: latency-bound fix. 4 threads ("subs") per float4-quad, each sub
// handles 8 lights (24 channels per array -> 48 float4 loads/thread).
// 262144 threads = 4096 waves = 16 waves/CU. Partial sums (9 accum x 4 pixels)
// reduced via __shfl_xor butterfly within the 4-lane group. Subs 0..2 store
// one output plane each (coalesced 256B segments).

constexpr int QROW = 16384;   // 65536 pixels / 4 per float4 per image plane
constexpr int CH   = 96;

__device__ __forceinline__ float fc(const float4 v, int j) {
    return j == 0 ? v.x : j == 1 ? v.y : j == 2 ? v.z : v.w;
}
__device__ __forceinline__ void setc(float4& v, int j, float x) {
    if (j == 0) v.x = x; else if (j == 1) v.y = x; else if (j == 2) v.z = x; else v.w = x;
}

__global__ __launch_bounds__(256, 4) void LS_44160853737780_kernel(
    const float4* __restrict__ img,
    const float4* __restrict__ light,
    float4* __restrict__ out)
{
    int t   = blockIdx.x * blockDim.x + threadIdx.x;
    int q   = t >> 2;          // quad (float4-column) index in [0, 65536)
    int sub = t & 3;           // which 8-light slice this thread handles
    int b   = q >> 14;
    int p   = q & 16383;

    // This thread's 24 channels start at light sub*8 -> channel sub*24.
    const float4* ib = img   + (size_t)(b * CH + sub * 24) * QROW + p;
    const float4* lb = light + (size_t)(b * CH + sub * 24) * QROW + p;

    float A00[4] = {0,0,0,0}, A01[4] = {0,0,0,0}, A02[4] = {0,0,0,0},
          A11[4] = {0,0,0,0}, A12[4] = {0,0,0,0}, A22[4] = {0,0,0,0},
          r0[4]  = {0,0,0,0}, r1[4]  = {0,0,0,0}, r2[4]  = {0,0,0,0};

    // 8 lights, processed 2 per iteration (12 float4 loads in flight/chunk),
    // fully unrolled so the scheduler can software-pipeline chunks.
    #pragma unroll
    for (int f = 0; f < 8; f += 2) {
        float4 i0x = ib[(3*f+0)*QROW], i0y = ib[(3*f+1)*QROW], i0z = ib[(3*f+2)*QROW];
        float4 i1x = ib[(3*f+3)*QROW], i1y = ib[(3*f+4)*QROW], i1z = ib[(3*f+5)*QROW];
        float4 l0x = lb[(3*f+0)*QROW], l0y = lb[(3*f+1)*QROW], l0z = lb[(3*f+2)*QROW];
        float4 l1x = lb[(3*f+3)*QROW], l1y = lb[(3*f+4)*QROW], l1z = lb[(3*f+5)*QROW];
        #pragma unroll
        for (int j = 0; j < 4; ++j) {
            {
                float x = fc(i0x,j), y = fc(i0y,j), z = fc(i0z,j);
                float I = sqrtf(x*x + y*y + z*z);
                float a = fc(l0x,j), c = fc(l0y,j), d = fc(l0z,j);
                A00[j] += a*a; A01[j] += a*c; A02[j] += a*d;
                A11[j] += c*c; A12[j] += c*d; A22[j] += d*d;
                r0[j]  += a*I; r1[j]  += c*I; r2[j]  += d*I;
            }
            {
                float x = fc(i1x,j), y = fc(i1y,j), z = fc(i1z,j);
                float I = sqrtf(x*x + y*y + z*z);
                float a = fc(l1x,j), c = fc(l1y,j), d = fc(l1z,j);
                A00[j] += a*a; A01[j] += a*c; A02[j] += a*d;
                A11[j] += c*c; A12[j] += c*d; A22[j] += d*d;
                r0[j]  += a*I; r1[j]  += c*I; r2[j]  += d*I;
            }
        }
    }

    // Butterfly reduce over the 4-lane group (xor 1, 2): every lane ends with
    // the full 32-light sums.
    #pragma unroll
    for (int m = 1; m <= 2; m <<= 1) {
        #pragma unroll
        for (int j = 0; j < 4; ++j) {
            A00[j] += __shfl_xor(A00[j], m);
            A01[j] += __shfl_xor(A01[j], m);
            A02[j] += __shfl_xor(A02[j], m);
            A11[j] += __shfl_xor(A11[j], m);
            A12[j] += __shfl_xor(A12[j], m);
            A22[j] += __shfl_xor(A22[j], m);
            r0[j]  += __shfl_xor(r0[j],  m);
            r1[j]  += __shfl_xor(r1[j],  m);
            r2[j]  += __shfl_xor(r2[j],  m);
        }
    }

    // Epilogue: 3x3 SPD solve via adjugate + normalize (all lanes, redundant).
    float4 o0, o1, o2;
    #pragma unroll
    for (int j = 0; j < 4; ++j) {
        float a00 = A00[j], a01 = A01[j], a02 = A02[j],
              a11 = A11[j], a12 = A12[j], a22 = A22[j];
        float c00 = a11*a22 - a12*a12;
        float c01 = a02*a12 - a01*a22;
        float c02 = a01*a12 - a02*a11;
        float c11 = a00*a22 - a02*a02;
        float c12 = a01*a02 - a00*a12;
        float c22 = a00*a11 - a01*a01;
        float det = a00*c00 + a01*c01 + a02*c02;
        float inv = 1.0f / det;
        float n0 = (c00*r0[j] + c01*r1[j] + c02*r2[j]) * inv;
        float n1 = (c01*r0[j] + c11*r1[j] + c12*r2[j]) * inv;
        float n2 = (c02*r0[j] + c12*r1[j] + c22*r2[j]) * inv;
        float nn = sqrtf(n0*n0 + n1*n1 + n2*n2);
        float s  = 1.0f / (nn + 1e-10f);
        setc(o0, j, n0*s);
        setc(o1, j, n1*s);
        setc(o2, j, n2*s);
    }

    // Subs 0..2 each store one output plane (16 lanes/plane per wave ->
    // 256B contiguous segments). Sub 3 idles on the store.
    if (sub < 3) {
        float4 v = (sub == 0) ? o0 : (sub == 1) ? o1 : o2;
        out[(size_t)(b * 3 + sub) * QROW + p] = v;
    }
}

extern "C" void kernel_launch(void* const* d_in, const int* in_sizes, int n_in,
                              void* d_out, int out_size, void* d_ws, size_t ws_size,
                              hipStream_t stream) {
    const float4* img   = (const float4*)d_in[0];
    const float4* light = (const float4*)d_in[1];
    float4* out = (float4*)d_out;
    // 65536 quads * 4 subs = 262144 threads; 256/block -> 1024 blocks.
    LS_44160853737780_kernel<<<dim3(1024), dim3(256), 0, stream>>>(img, light, out);
}